// Round 1
// baseline (55.198 us; speedup 1.0000x reference)
//
#include <hip/hip_runtime.h>

// BidPrefix: per row of inputs[B, 302]:
//   rates = row[0:300]; bid = (int)row[300]; mp = (int)row[301]
//   cpz[k] = prod(rates[0:k]), k in [0,300]
//   out[row] = { cpz[bid], cpz[mp+1], cpz[mp] }
//
// One wave64 per row. Lane l owns rates[5l .. 5l+4] (contiguous segment),
// computes in-segment prefix products, then a log2(64)-step shfl_up
// multiplicative scan produces the exclusive cross-lane prefix. Each of the
// 3 gathers is excl[idx/5] * q[idx%5] pulled from lane idx/5 via __shfl.
// Only rates[0 .. max(bid, mp+1)) are loaded -> skips ~1/3 of HBM traffic.

constexpr int SEQ  = 300;
constexpr int NCOL = 302;

__global__ __launch_bounds__(256) void bidprefix_kernel(
    const float* __restrict__ in, float* __restrict__ out, int batch)
{
    const int lane = threadIdx.x & 63;
    const int wid  = threadIdx.x >> 6;
    const int row  = blockIdx.x * 4 + wid;
    if (row >= batch) return;

    const float* __restrict__ rp = in + (size_t)row * NCOL;

    // Wave-uniform loads (all lanes hit same address -> broadcast).
    const int bid    = (int)rp[SEQ];
    const int mp     = (int)rp[SEQ + 1];
    const int maxidx = max(bid, mp + 1);   // #rates actually needed (<= 300)

    // Lane-owned contiguous segment [5*lane, 5*lane+5); out-of-range -> 1.0.
    const int base = 5 * lane;
    const float v0 = (base + 0 < maxidx) ? rp[base + 0] : 1.f;
    const float v1 = (base + 1 < maxidx) ? rp[base + 1] : 1.f;
    const float v2 = (base + 2 < maxidx) ? rp[base + 2] : 1.f;
    const float v3 = (base + 3 < maxidx) ? rp[base + 3] : 1.f;
    const float v4 = (base + 4 < maxidx) ? rp[base + 4] : 1.f;

    // In-segment prefix products: q[r] = prod of first r elems of my segment.
    const float q0 = 1.f;
    const float q1 = v0;
    const float q2 = q1 * v1;
    const float q3 = q2 * v2;
    const float q4 = q3 * v3;
    const float q5 = q4 * v4;

    // Inclusive multiplicative scan of segment products across 64 lanes.
    float run = q5;
    #pragma unroll
    for (int s = 1; s < 64; s <<= 1) {
        const float t = __shfl_up(run, s, 64);
        if (lane >= s) run *= t;
    }
    // Exclusive prefix: product of all full segments before mine.
    float excl = __shfl_up(run, 1, 64);
    if (lane == 0) excl = 1.f;

    // cpz[idx] = excl[idx/5] * q[idx%5], pulled from lane idx/5.
    auto answer = [&](int idx) -> float {
        const int b = idx / 5;
        const int r = idx - 5 * b;
        const float qr = (r == 0) ? q0
                       : (r == 1) ? q1
                       : (r == 2) ? q2
                       : (r == 3) ? q3
                       :            q4;
        return __shfl(excl * qr, b, 64);
    };

    const float o0 = answer(bid);
    const float o1 = answer(mp + 1);
    const float o2 = answer(mp);

    if (lane == 0) {
        float* __restrict__ op = out + (size_t)row * 3;
        op[0] = o0;
        op[1] = o1;
        op[2] = o2;
    }
}

extern "C" void kernel_launch(void* const* d_in, const int* in_sizes, int n_in,
                              void* d_out, int out_size, void* d_ws, size_t ws_size,
                              hipStream_t stream) {
    const float* in = (const float*)d_in[0];
    float* out      = (float*)d_out;
    const int batch = in_sizes[0] / NCOL;   // 200000

    const int rows_per_block = 4;           // 4 waves of 64 per block
    dim3 block(256);
    dim3 grid((batch + rows_per_block - 1) / rows_per_block);
    bidprefix_kernel<<<grid, block, 0, stream>>>(in, out, batch);
}

// Round 2
// 50.147 us; speedup vs baseline: 1.1007x; 1.1007x over previous
//
#include <hip/hip_runtime.h>

// BidPrefix: per row of inputs[B, 302]:
//   rates = row[0:300]; bid = (int)row[300]; mp = (int)row[301]
//   cpz[k] = prod(rates[0:k]); out[row] = { cpz[bid], cpz[mp+1], cpz[mp] }
//
// One wave64 per FOUR rows (phase-split for memory-level parallelism):
//   phase 1: issue bid/mp loads for all 4 rows (dwordx2 each)
//   phase 2: issue all 4x5 rate loads, unconditional w/ clamped address
//            (lanes beyond maxidx re-read the L1-resident tail line -> no
//             extra HBM traffic; keeps the ~25% tail-skip saving)
//   phase 3: per row: in-register segment prefixes + 6-step shfl_up
//            multiplicative scan + 3 shfl gathers; lanes 0..2 store.

constexpr int SEQ  = 300;
constexpr int NCOL = 302;
constexpr int RPW  = 4;    // rows per wave

__global__ __launch_bounds__(256) void bidprefix_kernel(
    const float* __restrict__ in, float* __restrict__ out, int batch)
{
    const int lane = threadIdx.x & 63;
    const int wid  = threadIdx.x >> 6;
    const int row0 = (blockIdx.x * 4 + wid) * RPW;
    if (row0 >= batch) return;

    // Clamped row ids keep every load in-bounds for a partial tail group.
    int rr[RPW];
    #pragma unroll
    for (int r = 0; r < RPW; ++r) rr[r] = min(row0 + r, batch - 1);

    // ---- Phase 1: all index loads in flight together ----
    float2 bm[RPW];
    #pragma unroll
    for (int r = 0; r < RPW; ++r) {
        const float* rp = in + (size_t)rr[r] * NCOL;
        bm[r] = *reinterpret_cast<const float2*>(rp + SEQ);  // 8B-aligned
    }

    // ---- Phase 2: all rate loads in flight together ----
    const int base = 5 * lane;
    int   bid[RPW], mp[RPW];
    float v[RPW][5];
    #pragma unroll
    for (int r = 0; r < RPW; ++r) {
        bid[r] = (int)bm[r].x;
        mp[r]  = (int)bm[r].y;
        const int maxi = max(bid[r], mp[r] + 1);   // #rates needed (<= 300)
        const float* rp = in + (size_t)rr[r] * NCOL;
        #pragma unroll
        for (int i = 0; i < 5; ++i) {
            const bool ok = (base + i) < maxi;
            const int  a  = ok ? (base + i) : SEQ; // OOR lanes hit resident line
            const float x = rp[a];
            v[r][i] = ok ? x : 1.f;
        }
    }

    // ---- Phase 3: scan + gather + store, 4 rows back-to-back (ILP) ----
    #pragma unroll
    for (int r = 0; r < RPW; ++r) {
        const float q1 = v[r][0];
        const float q2 = q1 * v[r][1];
        const float q3 = q2 * v[r][2];
        const float q4 = q3 * v[r][3];
        const float q5 = q4 * v[r][4];

        float run = q5;
        #pragma unroll
        for (int s = 1; s < 64; s <<= 1) {
            const float t = __shfl_up(run, s, 64);
            if (lane >= s) run *= t;
        }
        float excl = __shfl_up(run, 1, 64);
        if (lane == 0) excl = 1.f;

        const int idxs[3] = { bid[r], mp[r] + 1, mp[r] };
        float o[3];
        #pragma unroll
        for (int j = 0; j < 3; ++j) {
            const int b  = idxs[j] / 5;
            const int rm = idxs[j] - 5 * b;
            const float qr = (rm == 0) ? 1.f
                           : (rm == 1) ? q1
                           : (rm == 2) ? q2
                           : (rm == 3) ? q3
                           :             q4;
            o[j] = __shfl(excl * qr, b, 64);   // cpz[idx] from lane idx/5
        }

        if (lane < 3 && (row0 + r) < batch) {
            const float ov = (lane == 0) ? o[0] : (lane == 1) ? o[1] : o[2];
            out[(size_t)(row0 + r) * 3 + lane] = ov;
        }
    }
}

extern "C" void kernel_launch(void* const* d_in, const int* in_sizes, int n_in,
                              void* d_out, int out_size, void* d_ws, size_t ws_size,
                              hipStream_t stream) {
    const float* in = (const float*)d_in[0];
    float* out      = (float*)d_out;
    const int batch = in_sizes[0] / NCOL;            // 200000

    const int rows_per_block = 4 * RPW;              // 4 waves x RPW rows
    dim3 block(256);
    dim3 grid((batch + rows_per_block - 1) / rows_per_block);
    bidprefix_kernel<<<grid, block, 0, stream>>>(in, out, batch);
}

// Round 3
// 41.702 us; speedup vs baseline: 1.3236x; 1.2025x over previous
//
#include <hip/hip_runtime.h>

// BidPrefix: per row of inputs[B, 302]:
//   rates = row[0:300]; bid = (int)row[300]; mp = (int)row[301]
//   cpz[k] = prod(rates[0:k]); out[row] = { cpz[bid], cpz[mp+1], cpz[mp] }
//
// One wave64 per 4-row slab (4832 B, 16B-aligned since 4832 = 16*302):
//  P1: 4 wave-uniform float2 loads -> bid/mp/maxidx per row.
//  P2: flat float4 copy of slab -> private LDS. Perfectly coalesced
//      (lane-stride == access size == 16B). Per-float4 tail skip:
//      need = (col < maxidx_row) || (col == 300 /*carries next row head*/);
//      skipped lanes clamp to slab offset 0 (resident line, no extra HBM).
//      Garbage beyond maxidx is harmless: queries at idx only read lane
//      idx/5, whose excl/q use exclusively elements < idx <= maxidx.
//  P3: per row: lane l reads contiguous seg [5l,5l+5) from LDS
//      (banks 5l+i mod 32 -> 2-way aliasing = free), in-register segment
//      prefixes + 6-step shfl_up multiplicative scan + 3 shfl gathers.
//  No __syncthreads anywhere (slabs are wave-private) -> free wave overlap.

constexpr int SEQ   = 300;
constexpr int NCOL  = 302;
constexpr int RPW   = 4;               // rows per wave-slab
constexpr int WPB   = 4;               // waves per block
constexpr int SLABF = NCOL * RPW;      // 1208 floats per slab

__global__ __launch_bounds__(256) void bidprefix_kernel(
    const float* __restrict__ in, float* __restrict__ out, int batch)
{
    __shared__ __align__(16) float lds[WPB * SLABF + 32]; // +pad: lanes 60-63 overread

    const int lane = threadIdx.x & 63;
    const int wid  = threadIdx.x >> 6;
    const int slab = blockIdx.x * WPB + wid;
    const int row0 = slab * RPW;
    if (row0 >= batch) return;

    float* sl = lds + wid * SLABF;
    const float* g = in + (size_t)row0 * NCOL;

    // ---- Phase 1: wave-uniform index loads (one line each, broadcast) ----
    const float2 bm0 = *reinterpret_cast<const float2*>(g + 0 * NCOL + SEQ);
    const float2 bm1 = *reinterpret_cast<const float2*>(g + 1 * NCOL + SEQ);
    const float2 bm2 = *reinterpret_cast<const float2*>(g + 2 * NCOL + SEQ);
    const float2 bm3 = *reinterpret_cast<const float2*>(g + 3 * NCOL + SEQ);

    const int m0 = max((int)bm0.x, (int)bm0.y + 1);   // #rates needed, row 0
    const int m1 = max((int)bm1.x, (int)bm1.y + 1);
    const int m2 = max((int)bm2.x, (int)bm2.y + 1);
    const int m3 = max((int)bm3.x, (int)bm3.y + 1);

    // ---- Phase 2: coalesced float4 slab copy with per-float4 tail skip ----
    float4 vv[5];
    int    fa[5];
    bool   va[5];
    #pragma unroll
    for (int c = 0; c < 5; ++c) {
        const int  f     = 256 * c + 4 * lane;        // dword index in slab
        const bool valid = f < SLABF;                 // false only for c==4, lane>=46
        const int  r     = (f >= 3 * NCOL) ? 3 : (f >= 2 * NCOL) ? 2
                         : (f >= NCOL)     ? 1 : 0;
        const int  col   = f - r * NCOL;
        const int  mr    = (r == 0) ? m0 : (r == 1) ? m1 : (r == 2) ? m2 : m3;
        const bool need  = valid && ((col < mr) || (col == 300));
        fa[c] = f;
        va[c] = valid;
        vv[c] = *reinterpret_cast<const float4*>(g + (need ? f : 0));
    }
    #pragma unroll
    for (int c = 0; c < 5; ++c) {
        if (va[c]) *reinterpret_cast<float4*>(sl + fa[c]) = vv[c];
    }

    // ---- Phase 3: per-row scan + gather + store ----
    const int base = 5 * lane;
    #pragma unroll
    for (int r = 0; r < RPW; ++r) {
        const float* rs = sl + r * NCOL;
        const float x0 = rs[base + 0];
        const float x1 = rs[base + 1];
        const float x2 = rs[base + 2];
        const float x3 = rs[base + 3];
        const float x4 = rs[base + 4];

        const float q1 = x0;
        const float q2 = q1 * x1;
        const float q3 = q2 * x2;
        const float q4 = q3 * x3;
        const float q5 = q4 * x4;

        float run = q5;
        #pragma unroll
        for (int s = 1; s < 64; s <<= 1) {
            const float t = __shfl_up(run, s, 64);
            if (lane >= s) run *= t;
        }
        float excl = __shfl_up(run, 1, 64);
        if (lane == 0) excl = 1.f;

        const float2 bm = (r == 0) ? bm0 : (r == 1) ? bm1 : (r == 2) ? bm2 : bm3;
        const int bid = (int)bm.x;
        const int mp  = (int)bm.y;

        const int idxs[3] = { bid, mp + 1, mp };
        float o[3];
        #pragma unroll
        for (int j = 0; j < 3; ++j) {
            const int b  = idxs[j] / 5;
            const int rm = idxs[j] - 5 * b;
            const float qr = (rm == 0) ? 1.f
                           : (rm == 1) ? q1
                           : (rm == 2) ? q2
                           : (rm == 3) ? q3
                           :             q4;
            o[j] = __shfl(excl * qr, b, 64);          // cpz[idx] from lane idx/5
        }

        if (lane < 3) {
            const float ov = (lane == 0) ? o[0] : (lane == 1) ? o[1] : o[2];
            out[(size_t)(row0 + r) * 3 + lane] = ov;
        }
    }
}

extern "C" void kernel_launch(void* const* d_in, const int* in_sizes, int n_in,
                              void* d_out, int out_size, void* d_ws, size_t ws_size,
                              hipStream_t stream) {
    const float* in = (const float*)d_in[0];
    float* out      = (float*)d_out;
    const int batch = in_sizes[0] / NCOL;             // 200000

    const int rows_per_block = WPB * RPW;             // 16
    dim3 block(256);
    dim3 grid((batch + rows_per_block - 1) / rows_per_block);
    bidprefix_kernel<<<grid, block, 0, stream>>>(in, out, batch);
}

// Round 5
// 35.732 us; speedup vs baseline: 1.5448x; 1.1671x over previous
//
#include <hip/hip_runtime.h>

// BidPrefix: per row of inputs[B, 302]:
//   rates = row[0:300]; bid = (int)row[300]; mp = (int)row[301]
//   cpz[k] = prod(rates[0:k]); out[row] = { cpz[bid], cpz[mp+1], cpz[mp] }
//
// One wave64 per 4-row slab (4832 B, 16B-aligned since 4832 = 16*302):
//  P1: ONE dwordx2 load (lane&3 selects row) -> 4x(bid,mp); readlane -> SGPRs.
//  P2: flat float4 copy of slab -> private LDS, perfectly coalesced, with
//      per-float4 tail skip (need = col < maxidx_row || col == 300); skipped
//      lanes clamp to slab offset 0 (resident line, no extra HBM traffic).
//  P3: lane l reads contiguous seg [5l,5l+5) from LDS, builds in-segment
//      prefixes, then a 6-step DPP multiplicative scan (VALU pipe, zero
//      ds_bpermute): row_shr:1/2/4/8 + row_bcast15(0xa) + row_bcast31(0xc),
//      out-of-range lanes get old=1.0 (multiplicative identity).
//      Queries are wave-uniform -> scalar b=idx/5, gathers via v_readlane
//      (VALU), cpz[idx] = run[b-1] * qsel[b]. Garbage beyond maxidx only
//      propagates to HIGHER lanes; queried lanes (<= b) are clean.
//  No __syncthreads (slabs wave-private); DS pipe now only 5 writes + 20
//  reads per slab -> HBM-bound.

constexpr int SEQ   = 300;
constexpr int NCOL  = 302;
constexpr int RPW   = 4;               // rows per wave-slab
constexpr int WPB   = 4;               // waves per block
constexpr int SLABF = NCOL * RPW;      // 1208 floats per slab

template <int CTRL, int ROW_MASK>
__device__ __forceinline__ float mul_scan_step(float run) {
    // t = DPP-moved 'run'; lanes with no valid source (or masked rows) get 1.0
    const int t = __builtin_amdgcn_update_dpp(
        __float_as_int(1.0f), __float_as_int(run), CTRL, ROW_MASK, 0xf, false);
    return run * __int_as_float(t);
}

__global__ __launch_bounds__(256) void bidprefix_kernel(
    const float* __restrict__ in, float* __restrict__ out, int batch)
{
    __shared__ __align__(16) float lds[WPB * SLABF + 32]; // +pad: lanes 60-63 overread

    const int lane = threadIdx.x & 63;
    const int wid  = threadIdx.x >> 6;
    const int row0 = (blockIdx.x * WPB + wid) * RPW;
    if (row0 >= batch) return;

    float* sl = lds + wid * SLABF;
    const float* g = in + (size_t)row0 * NCOL;

    // ---- Phase 1: one dwordx2 covers all 4 rows' (bid,mp) ----
    const int rl = lane & 3;
    const float2 bmv = *reinterpret_cast<const float2*>(g + rl * NCOL + SEQ);
    const int ibv = (int)bmv.x;          // per-lane cvt, rows replicated x16
    const int imv = (int)bmv.y;
    const int bid0 = __builtin_amdgcn_readlane(ibv, 0);
    const int bid1 = __builtin_amdgcn_readlane(ibv, 1);
    const int bid2 = __builtin_amdgcn_readlane(ibv, 2);
    const int bid3 = __builtin_amdgcn_readlane(ibv, 3);
    const int mp0  = __builtin_amdgcn_readlane(imv, 0);
    const int mp1  = __builtin_amdgcn_readlane(imv, 1);
    const int mp2  = __builtin_amdgcn_readlane(imv, 2);
    const int mp3  = __builtin_amdgcn_readlane(imv, 3);
    const int m0 = max(bid0, mp0 + 1);   // #rates needed per row (<= 300)
    const int m1 = max(bid1, mp1 + 1);
    const int m2 = max(bid2, mp2 + 1);
    const int m3 = max(bid3, mp3 + 1);

    // ---- Phase 2: coalesced float4 slab copy with per-float4 tail skip ----
    float4 vv[5];
    int    fa[5];
    bool   va[5];
    #pragma unroll
    for (int c = 0; c < 5; ++c) {
        const int  f     = 256 * c + 4 * lane;        // dword index in slab
        const bool valid = f < SLABF;                 // false only for c==4, lane>=46
        const int  r     = (f >= 3 * NCOL) ? 3 : (f >= 2 * NCOL) ? 2
                         : (f >= NCOL)     ? 1 : 0;
        const int  col   = f - r * NCOL;
        const int  mr    = (r == 0) ? m0 : (r == 1) ? m1 : (r == 2) ? m2 : m3;
        const bool need  = valid && ((col < mr) || (col == 300));
        fa[c] = f;
        va[c] = valid;
        vv[c] = *reinterpret_cast<const float4*>(g + (need ? f : 0));
    }
    #pragma unroll
    for (int c = 0; c < 5; ++c) {
        if (va[c]) *reinterpret_cast<float4*>(sl + fa[c]) = vv[c];
    }

    // ---- Phase 3: per-row DPP scan + scalar gathers + store ----
    const int base = 5 * lane;
    #pragma unroll
    for (int r = 0; r < RPW; ++r) {
        const float* rs = sl + r * NCOL;
        const float x0 = rs[base + 0];
        const float x1 = rs[base + 1];
        const float x2 = rs[base + 2];
        const float x3 = rs[base + 3];
        const float x4 = rs[base + 4];

        const float q1 = x0;
        const float q2 = q1 * x1;
        const float q3 = q2 * x2;
        const float q4 = q3 * x3;
        const float q5 = q4 * x4;

        // Inclusive multiplicative scan over 64 lanes, all on the VALU pipe.
        float run = q5;
        run = mul_scan_step<0x111, 0xf>(run);   // row_shr:1
        run = mul_scan_step<0x112, 0xf>(run);   // row_shr:2
        run = mul_scan_step<0x114, 0xf>(run);   // row_shr:4
        run = mul_scan_step<0x118, 0xf>(run);   // row_shr:8
        run = mul_scan_step<0x142, 0xa>(run);   // row_bcast15 -> rows 1,3
        run = mul_scan_step<0x143, 0xc>(run);   // row_bcast31 -> rows 2,3

        const int bid = (r == 0) ? bid0 : (r == 1) ? bid1 : (r == 2) ? bid2 : bid3;
        const int mp  = (r == 0) ? mp0  : (r == 1) ? mp1  : (r == 2) ? mp2  : mp3;

        const int idxs[3] = { bid, mp + 1, mp };
        float o[3];
        #pragma unroll
        for (int j = 0; j < 3; ++j) {
            const int idx = idxs[j];             // scalar (SGPR)
            const int b   = idx / 5;             // scalar magic-mul
            const int rm  = idx - 5 * b;
            const float qsel = (rm == 0) ? 1.f
                             : (rm == 1) ? q1
                             : (rm == 2) ? q2
                             : (rm == 3) ? q3
                             :             q4;
            const float seg = __int_as_float(
                __builtin_amdgcn_readlane(__float_as_int(qsel), b));
            const int   bp  = (b > 0) ? (b - 1) : 0;
            const float pre = __int_as_float(
                __builtin_amdgcn_readlane(__float_as_int(run), bp));
            o[j] = (b > 0 ? pre : 1.f) * seg;    // cpz[idx]
        }

        if (lane < 3) {
            const float ov = (lane == 0) ? o[0] : (lane == 1) ? o[1] : o[2];
            out[(size_t)(row0 + r) * 3 + lane] = ov;
        }
    }
}

extern "C" void kernel_launch(void* const* d_in, const int* in_sizes, int n_in,
                              void* d_out, int out_size, void* d_ws, size_t ws_size,
                              hipStream_t stream) {
    const float* in = (const float*)d_in[0];
    float* out      = (float*)d_out;
    const int batch = in_sizes[0] / NCOL;             // 200000

    const int rows_per_block = WPB * RPW;             // 16
    dim3 block(256);
    dim3 grid((batch + rows_per_block - 1) / rows_per_block);
    bidprefix_kernel<<<grid, block, 0, stream>>>(in, out, batch);
}